// Round 8
// baseline (746.368 us; speedup 1.0000x reference)
//
#include <hip/hip_runtime.h>

#define NNODES 50000
#define NEDGES 800000
#define NGRAPH 500
#define CH 100
#define CIN0 33
#define BN_EPS 1e-5f

#define SCAN_TPB 256
#define SCAN_IPT 4
#define SCAN_TILE (SCAN_TPB * SCAN_IPT)
#define SCAN_BLOCKS ((NNODES + SCAN_TILE - 1) / SCAN_TILE)

// ---------------- init: zero histogram counters + BN stats + pool accumulator ----------------
__global__ void k_init(int* __restrict__ cnt, float* __restrict__ stats,
                       float* __restrict__ gbuf) {
    int i = blockIdx.x * blockDim.x + threadIdx.x;
    if (i < NNODES) cnt[i] = 0;
    if (i < NGRAPH * CH) gbuf[i] = 0.f;   // NGRAPH*CH == NNODES
    if (i < 1024) stats[i] = 0.f;
}

// ---------------- in-degree histogram over dst ----------------
__global__ void k_hist(const int* __restrict__ dst, int* __restrict__ cnt) {
    int e = blockIdx.x * blockDim.x + threadIdx.x;
    if (e < NEDGES) atomicAdd(&cnt[dst[e]], 1);
}

// ---------------- exclusive scan of cnt -> rowptr; also dinv = rsqrt(cnt+1) ----------------
__global__ void k_scan1(const int* __restrict__ cnt, int* __restrict__ rowptr,
                        int* __restrict__ blkSums, float* __restrict__ dinv) {
    __shared__ int ts[SCAN_TPB];
    int tid = threadIdx.x;
    int base = blockIdx.x * SCAN_TILE + tid * SCAN_IPT;
    int v[SCAN_IPT];
    int s = 0;
    #pragma unroll
    for (int j = 0; j < SCAN_IPT; ++j) {
        int i = base + j;
        v[j] = (i < NNODES) ? cnt[i] : 0;
        if (i < NNODES) dinv[i] = rsqrtf((float)(v[j] + 1));
        s += v[j];
    }
    ts[tid] = s;
    __syncthreads();
    for (int off = 1; off < SCAN_TPB; off <<= 1) {
        int add = (tid >= off) ? ts[tid - off] : 0;
        __syncthreads();
        ts[tid] += add;
        __syncthreads();
    }
    int run = ts[tid] - s;  // exclusive prefix within block
    #pragma unroll
    for (int j = 0; j < SCAN_IPT; ++j) {
        int i = base + j;
        if (i < NNODES) rowptr[i] = run;
        run += v[j];
    }
    if (tid == SCAN_TPB - 1) blkSums[blockIdx.x] = ts[tid];
}

__global__ void k_scan2(const int* __restrict__ blkSums, int* __restrict__ blkOff) {
    if (threadIdx.x == 0) {
        int run = 0;
        for (int i = 0; i < SCAN_BLOCKS; ++i) { blkOff[i] = run; run += blkSums[i]; }
    }
}

__global__ void k_scan3(int* __restrict__ rowptr, int* __restrict__ cursor,
                        const int* __restrict__ blkOff) {
    int off = blkOff[blockIdx.x];
    int base = blockIdx.x * SCAN_TILE + threadIdx.x * SCAN_IPT;
    #pragma unroll
    for (int j = 0; j < SCAN_IPT; ++j) {
        int i = base + j;
        if (i < NNODES) {
            int vv = rowptr[i] + off;
            rowptr[i] = vv;
            cursor[i] = vv;
        }
    }
    if (blockIdx.x == 0 && threadIdx.x == 0) rowptr[NNODES] = NEDGES;
}

// ---------------- scatter edges into CSR (by dst); pack (src, dinv[src]) ----------------
__global__ void k_scatter(const int* __restrict__ src, const int* __restrict__ dst,
                          const float* __restrict__ dinv, int* __restrict__ cursor,
                          int2* __restrict__ ew) {
    int e = blockIdx.x * blockDim.x + threadIdx.x;
    if (e < NEDGES) {
        int d = dst[e], s = src[e];
        int pos = atomicAdd(&cursor[d], 1);
        ew[pos] = make_int2(s, __float_as_int(dinv[s]));
    }
}

// ---------------- fused layer: z = (S . f(h)) @ W + b, with BN-stats of z ----------------
// f(v) = BN ? relu(v*scale+shift) : v (scale/shift from prev-layer raw stats).
// One wave per node (8 nodes/wave, 8 waves/block). Gather phase: 64 edge
// descriptors loaded coalesced + shfl-broadcast; lane holds input channels
// (2*lane, 2*lane+1) [C even] or channel lane [C odd]. Matvec phase: shfl-
// broadcast agg values, W read from LDS (staged once per block; float2 reads
// are 2-way bank aliased = free). z written by lanes 0..49 (channels 2c,2c+1);
// per-lane BN stats accumulated and block-reduced at the end.
template<int C, bool BN>
__global__ __launch_bounds__(512) void k_layer(
    const float* __restrict__ h, float* __restrict__ z,
    const int* __restrict__ rowptr, const int2* __restrict__ ew,
    const float* __restrict__ dinv,
    const float* __restrict__ psum, const float* __restrict__ psq,
    const float* __restrict__ pgamma, const float* __restrict__ pbeta,
    const float* __restrict__ W, const float* __restrict__ bias,
    float* __restrict__ gsum, float* __restrict__ gsq) {
    __shared__ __align__(16) float wS[C * CH];
    __shared__ float sSum[CH], sSq[CH];
    int tid = threadIdx.x;
    for (int i = tid; i < C * CH; i += 512) wS[i] = W[i];
    if (tid < CH) { sSum[tid] = 0.f; sSq[tid] = 0.f; }
    __syncthreads();

    int wid = tid >> 6, lane = tid & 63;
    bool oact = lane < CH / 2;
    float2 bv = make_float2(0.f, 0.f);
    if (oact) bv = ((const float2*)bias)[lane];
    float csx = 0.f, csy = 0.f, cqx = 0.f, cqy = 0.f;
    constexpr float invN = 1.f / NNODES;

    // BN constants for the input channels (even-C path only)
    float scx = 0.f, scy = 0.f, shx = 0.f, shy = 0.f;
    if constexpr (BN) {
        if (lane < C / 2) {
            float2 s2 = ((const float2*)psum)[lane];
            float2 q2 = ((const float2*)psq)[lane];
            float2 g2 = ((const float2*)pgamma)[lane];
            float2 b2 = ((const float2*)pbeta)[lane];
            float mx = s2.x * invN, my = s2.y * invN;
            float vx = q2.x * invN - mx * mx, vy = q2.y * invN - my * my;
            scx = g2.x * rsqrtf(vx + BN_EPS); shx = b2.x - mx * scx;
            scy = g2.y * rsqrtf(vy + BN_EPS); shy = b2.y - my * scy;
        }
    }

    for (int i = 0; i < 8; ++i) {
        int node = (blockIdx.x * 8 + wid) * 8 + i;
        if (node >= NNODES) break;                 // wave-uniform
        int p0 = rowptr[node], p1 = rowptr[node + 1];
        float di = dinv[node];

        float ax = 0.f, ay = 0.f;   // C-even agg (channels 2*lane, 2*lane+1)
        float a0s = 0.f;            // C-odd agg (channel lane)

        if constexpr ((C & 1) == 0) {
            bool act = lane < C / 2;
            for (int base = p0; base < p1; base += 64) {
                int nn = p1 - base; if (nn > 64) nn = 64;
                int2 e = make_int2(0, 0);
                if (lane < nn) e = ew[base + lane];
                int myc = e.x; float myw = __int_as_float(e.y);
                int j = 0;
                for (; j + 8 <= nn; j += 8) {
                    int s[8]; float w[8];
                    #pragma unroll
                    for (int t = 0; t < 8; ++t) { s[t] = __shfl(myc, j + t); w[t] = __shfl(myw, j + t); }
                    if (act) {
                        float2 v[8];
                        #pragma unroll
                        for (int t = 0; t < 8; ++t) v[t] = ((const float2*)(h + (size_t)s[t] * C))[lane];
                        #pragma unroll
                        for (int t = 0; t < 8; ++t) {
                            float vx = v[t].x, vy = v[t].y;
                            if (BN) {
                                vx = fmaxf(vx * scx + shx, 0.f);
                                vy = fmaxf(vy * scy + shy, 0.f);
                            }
                            ax += w[t] * vx; ay += w[t] * vy;
                        }
                    }
                }
                for (; j < nn; ++j) {
                    int s0 = __shfl(myc, j);
                    float w0 = __shfl(myw, j);
                    if (act) {
                        float2 v = ((const float2*)(h + (size_t)s0 * C))[lane];
                        float vx = v.x, vy = v.y;
                        if (BN) {
                            vx = fmaxf(vx * scx + shx, 0.f);
                            vy = fmaxf(vy * scy + shy, 0.f);
                        }
                        ax += w0 * vx; ay += w0 * vy;
                    }
                }
            }
            if (act) {
                float2 hv = ((const float2*)(h + (size_t)node * C))[lane];
                float hx = hv.x, hy = hv.y;
                if (BN) {
                    hx = fmaxf(hx * scx + shx, 0.f);
                    hy = fmaxf(hy * scy + shy, 0.f);
                }
                ax = di * (ax + di * hx);
                ay = di * (ay + di * hy);
            }
        } else {
            bool act = lane < C;
            for (int base = p0; base < p1; base += 64) {
                int nn = p1 - base; if (nn > 64) nn = 64;
                int2 e = make_int2(0, 0);
                if (lane < nn) e = ew[base + lane];
                int myc = e.x; float myw = __int_as_float(e.y);
                int j = 0;
                for (; j + 8 <= nn; j += 8) {
                    int s[8]; float w[8];
                    #pragma unroll
                    for (int t = 0; t < 8; ++t) { s[t] = __shfl(myc, j + t); w[t] = __shfl(myw, j + t); }
                    if (act) {
                        float v[8];
                        #pragma unroll
                        for (int t = 0; t < 8; ++t) v[t] = h[(size_t)s[t] * C + lane];
                        #pragma unroll
                        for (int t = 0; t < 8; ++t) a0s += w[t] * v[t];
                    }
                }
                for (; j < nn; ++j) {
                    int s0 = __shfl(myc, j);
                    float w0 = __shfl(myw, j);
                    if (act) a0s += w0 * h[(size_t)s0 * C + lane];
                }
            }
            if (act) {
                float hv = h[(size_t)node * C + lane];
                a0s = di * (a0s + di * hv);
            }
        }

        // ---- in-wave matvec: z[c] = sum_k a[k] * W[k][c] + b[c] ----
        float zx = bv.x, zy = bv.y;
        if constexpr ((C & 1) == 0) {
            #pragma unroll 5
            for (int k = 0; k < C / 2; ++k) {
                float a0 = __shfl(ax, k);
                float a1 = __shfl(ay, k);
                if (oact) {
                    float2 w0 = ((const float2*)(wS + (2 * k) * CH))[lane];
                    float2 w1 = ((const float2*)(wS + (2 * k + 1) * CH))[lane];
                    zx += a0 * w0.x + a1 * w1.x;
                    zy += a0 * w0.y + a1 * w1.y;
                }
            }
        } else {
            #pragma unroll 3
            for (int k = 0; k < C; ++k) {
                float a0 = __shfl(a0s, k);
                if (oact) {
                    float2 w0 = ((const float2*)(wS + k * CH))[lane];
                    zx += a0 * w0.x;
                    zy += a0 * w0.y;
                }
            }
        }
        if (oact) {
            ((float2*)(z + (size_t)node * CH))[lane] = make_float2(zx, zy);
            csx += zx; csy += zy; cqx += zx * zx; cqy += zy * zy;
        }
    }

    if (oact) {
        atomicAdd(&sSum[2 * lane], csx); atomicAdd(&sSum[2 * lane + 1], csy);
        atomicAdd(&sSq[2 * lane], cqx);  atomicAdd(&sSq[2 * lane + 1], cqy);
    }
    __syncthreads();
    if (tid < CH) { atomicAdd(&gsum[tid], sSum[tid]); atomicAdd(&gsq[tid], sSq[tid]); }
}

// ---------------- global_add_pool of BN(z) (no relu); 4 row-chunks per graph ----------------
__global__ void k_pool(const float* __restrict__ Zl, const int* __restrict__ batch,
                       const float* __restrict__ gsum, const float* __restrict__ gsq,
                       const float* __restrict__ gamma, const float* __restrict__ beta,
                       float* __restrict__ g) {
    int gid = blockIdx.x;
    int part = blockIdx.y;
    int lo = 0, hi = NNODES;
    while (lo < hi) { int mid = (lo + hi) >> 1; if (batch[mid] < gid) lo = mid + 1; else hi = mid; }
    int start = lo;
    hi = NNODES;
    while (lo < hi) { int mid = (lo + hi) >> 1; if (batch[mid] < gid + 1) lo = mid + 1; else hi = mid; }
    int end = lo;
    int len = end - start;
    int cb = (len + 3) >> 2;
    int s = start + part * cb;
    int e = s + cb; if (e > end) e = end;
    if (s >= e) return;
    int c = threadIdx.x;
    if (c >= CH) return;
    float mean = gsum[c] * (1.f / NNODES);
    float var = gsq[c] * (1.f / NNODES) - mean * mean;
    float sc = gamma[c] * rsqrtf(var + BN_EPS);
    float sh = beta[c] - mean * sc;
    float acc = 0.f;
    for (int r = s; r < e; ++r) acc += Zl[(size_t)r * CH + c];
    atomicAdd(&g[gid * CH + c], acc * sc + (float)(e - s) * sh);
}

// ---------------- out = leakyrelu(g @ Wout + bout, 0.1) ----------------
__global__ __launch_bounds__(256) void k_out(const float* __restrict__ g,
                                             const float* __restrict__ Wout,
                                             const float* __restrict__ bout,
                                             float* __restrict__ out) {
    __shared__ float gS[CH];
    int gid = blockIdx.x, tid = threadIdx.x;
    if (tid < CH) gS[tid] = g[gid * CH + tid];
    __syncthreads();
    if (tid >= 200) return;
    float acc = bout[tid];
    for (int k = 0; k < CH; ++k) acc += gS[k] * Wout[k * 200 + tid];
    out[gid * 200 + tid] = acc > 0.f ? acc : 0.1f * acc;
}

extern "C" void kernel_launch(void* const* d_in, const int* in_sizes, int n_in,
                              void* d_out, int out_size, void* d_ws, size_t ws_size,
                              hipStream_t stream) {
    const float* x = (const float*)d_in[0];
    const int* ei = (const int*)d_in[1];
    const int* batch = (const int*)d_in[2];
    const float* W0 = (const float*)d_in[3];
    const float* Wrest = (const float*)d_in[4];
    const float* b = (const float*)d_in[5];
    const float* gamma = (const float*)d_in[6];
    const float* beta = (const float*)d_in[7];
    const float* Wout = (const float*)d_in[8];
    const float* bout = (const float*)d_in[9];
    float* out = (float*)d_out;
    const int* srcA = ei;
    const int* dstA = ei + NEDGES;

    char* wsb = (char*)d_ws;
    size_t off = 0;
    auto alloc = [&](size_t elems) -> void* {
        void* p = (void*)(wsb + off);
        off += ((elems + 7) & ~(size_t)7) * 4;
        return p;
    };
    int* cnt = (int*)alloc(NNODES);
    int* rowptr = (int*)alloc(NNODES + 1);
    int* cursor = (int*)alloc(NNODES);
    float* dinv = (float*)alloc(NNODES);
    int* scanBlk = (int*)alloc(64);
    int* scanOff = (int*)alloc(64);
    float* stats = (float*)alloc(1024);      // sums[4][128] | sumsq[4][128]
    int2* ew = (int2*)alloc(2 * (size_t)NEDGES);
    float* Z0 = (float*)alloc((size_t)NNODES * CH);
    float* Z1 = (float*)alloc((size_t)NNODES * CH);
    float* gbuf = (float*)alloc((size_t)NGRAPH * CH);
    (void)ws_size; (void)n_in; (void)in_sizes; (void)out_size;

    hipLaunchKernelGGL(k_init, dim3((NNODES + 255) / 256), dim3(256), 0, stream, cnt, stats, gbuf);
    hipLaunchKernelGGL(k_hist, dim3((NEDGES + 255) / 256), dim3(256), 0, stream, dstA, cnt);
    hipLaunchKernelGGL(k_scan1, dim3(SCAN_BLOCKS), dim3(SCAN_TPB), 0, stream, cnt, rowptr, scanBlk, dinv);
    hipLaunchKernelGGL(k_scan2, dim3(1), dim3(64), 0, stream, scanBlk, scanOff);
    hipLaunchKernelGGL(k_scan3, dim3(SCAN_BLOCKS), dim3(SCAN_TPB), 0, stream, rowptr, cursor, scanOff);
    hipLaunchKernelGGL(k_scatter, dim3((NEDGES + 255) / 256), dim3(256), 0, stream,
                       srcA, dstA, dinv, cursor, ew);

    const int LGRID = (NNODES + 63) / 64;   // 8 waves/block x 8 nodes/wave
    // layer 0: x -> Z0
    hipLaunchKernelGGL((k_layer<CIN0, false>), dim3(LGRID), dim3(512), 0, stream,
                       x, Z0, rowptr, ew, dinv,
                       (const float*)nullptr, (const float*)nullptr,
                       (const float*)nullptr, (const float*)nullptr,
                       W0, b, stats, stats + 512);
    // layers 1..3: ping-pong Z buffers
    float* zin = Z0; float* zout = Z1;
    for (int l = 1; l < 4; ++l) {
        hipLaunchKernelGGL((k_layer<CH, true>), dim3(LGRID), dim3(512), 0, stream,
                           zin, zout, rowptr, ew, dinv,
                           stats + (l - 1) * 128, stats + 512 + (l - 1) * 128,
                           gamma + (l - 1) * CH, beta + (l - 1) * CH,
                           Wrest + (l - 1) * 10000, b + l * CH,
                           stats + l * 128, stats + 512 + l * 128);
        float* t = zin; zin = zout; zout = t;
    }
    // zin now holds layer-3 output
    hipLaunchKernelGGL(k_pool, dim3(NGRAPH, 4), dim3(128), 0, stream, zin, batch,
                       stats + 3 * 128, stats + 512 + 3 * 128, gamma + 3 * CH, beta + 3 * CH, gbuf);
    hipLaunchKernelGGL(k_out, dim3(NGRAPH), dim3(256), 0, stream, gbuf, Wout, bout, out);
}

// Round 9
// 606.604 us; speedup vs baseline: 1.2304x; 1.2304x over previous
//
#include <hip/hip_runtime.h>

#define NNODES 50000
#define NEDGES 800000
#define NGRAPH 500
#define CH 100
#define CIN0 33
#define BN_EPS 1e-5f

#define SCAN_TPB 256
#define SCAN_IPT 4
#define SCAN_TILE (SCAN_TPB * SCAN_IPT)
#define SCAN_BLOCKS ((NNODES + SCAN_TILE - 1) / SCAN_TILE)

// ---------------- init: zero histogram counters + BN stats + pool accumulator ----------------
__global__ void k_init(int* __restrict__ cnt, float* __restrict__ stats,
                       float* __restrict__ gbuf) {
    int i = blockIdx.x * blockDim.x + threadIdx.x;
    if (i < NNODES) cnt[i] = 0;
    if (i < NGRAPH * CH) gbuf[i] = 0.f;   // NGRAPH*CH == NNODES
    if (i < 1024) stats[i] = 0.f;
}

// ---------------- in-degree histogram over dst ----------------
__global__ void k_hist(const int* __restrict__ dst, int* __restrict__ cnt) {
    int e = blockIdx.x * blockDim.x + threadIdx.x;
    if (e < NEDGES) atomicAdd(&cnt[dst[e]], 1);
}

// ---------------- exclusive scan of cnt -> rowptr; also dinv = rsqrt(cnt+1) ----------------
__global__ void k_scan1(const int* __restrict__ cnt, int* __restrict__ rowptr,
                        int* __restrict__ blkSums, float* __restrict__ dinv) {
    __shared__ int ts[SCAN_TPB];
    int tid = threadIdx.x;
    int base = blockIdx.x * SCAN_TILE + tid * SCAN_IPT;
    int v[SCAN_IPT];
    int s = 0;
    #pragma unroll
    for (int j = 0; j < SCAN_IPT; ++j) {
        int i = base + j;
        v[j] = (i < NNODES) ? cnt[i] : 0;
        if (i < NNODES) dinv[i] = rsqrtf((float)(v[j] + 1));
        s += v[j];
    }
    ts[tid] = s;
    __syncthreads();
    for (int off = 1; off < SCAN_TPB; off <<= 1) {
        int add = (tid >= off) ? ts[tid - off] : 0;
        __syncthreads();
        ts[tid] += add;
        __syncthreads();
    }
    int run = ts[tid] - s;  // exclusive prefix within block
    #pragma unroll
    for (int j = 0; j < SCAN_IPT; ++j) {
        int i = base + j;
        if (i < NNODES) rowptr[i] = run;
        run += v[j];
    }
    if (tid == SCAN_TPB - 1) blkSums[blockIdx.x] = ts[tid];
}

__global__ void k_scan2(const int* __restrict__ blkSums, int* __restrict__ blkOff) {
    if (threadIdx.x == 0) {
        int run = 0;
        for (int i = 0; i < SCAN_BLOCKS; ++i) { blkOff[i] = run; run += blkSums[i]; }
    }
}

__global__ void k_scan3(int* __restrict__ rowptr, int* __restrict__ cursor,
                        const int* __restrict__ blkOff) {
    int off = blkOff[blockIdx.x];
    int base = blockIdx.x * SCAN_TILE + threadIdx.x * SCAN_IPT;
    #pragma unroll
    for (int j = 0; j < SCAN_IPT; ++j) {
        int i = base + j;
        if (i < NNODES) {
            int vv = rowptr[i] + off;
            rowptr[i] = vv;
            cursor[i] = vv;
        }
    }
    if (blockIdx.x == 0 && threadIdx.x == 0) rowptr[NNODES] = NEDGES;
}

// ---------------- scatter edges into CSR (by dst); pack (src, dinv[src]) ----------------
__global__ void k_scatter(const int* __restrict__ src, const int* __restrict__ dst,
                          const float* __restrict__ dinv, int* __restrict__ cursor,
                          int2* __restrict__ ew) {
    int e = blockIdx.x * blockDim.x + threadIdx.x;
    if (e < NEDGES) {
        int d = dst[e], s = src[e];
        int pos = atomicAdd(&cursor[d], 1);
        ew[pos] = make_int2(s, __float_as_int(dinv[s]));
    }
}

// ---------------- aggregate with fused BN(+ReLU) on gathered rows ----------------
// a[i] = dinv[i]*( sum_e dinv[src]*f(h[src]) + dinv[i]*f(h[i]) ),
// f(v) = BN ? relu(v*scale+shift) : v, scale/shift computed inline from raw
// stats. One wave per node; 64 edge descriptors coalesced + shfl-broadcast;
// row gathers unrolled 16x (latency-bound: keep many loads in flight).
// Output row stride OS (>=C), pad cols zero-filled.
template<int C, int OS, bool BN>
__global__ __launch_bounds__(256) void k_aggregate(
    const float* __restrict__ h, float* __restrict__ a, const int* __restrict__ rowptr,
    const int2* __restrict__ ew, const float* __restrict__ dinv,
    const float* __restrict__ gsum, const float* __restrict__ gsq,
    const float* __restrict__ gamma, const float* __restrict__ beta) {
    int node = (blockIdx.x * 256 + threadIdx.x) >> 6;
    int lane = threadIdx.x & 63;
    if (node >= NNODES) return;
    int p0 = rowptr[node], p1 = rowptr[node + 1];
    float di = dinv[node];
    constexpr float invN = 1.f / NNODES;

    if constexpr ((C & 1) == 0) {
        constexpr int HALF = C / 2;            // 50 for C=100
        bool act = lane < HALF;
        float scx = 0.f, scy = 0.f, shx = 0.f, shy = 0.f;
        if (BN && act) {
            float2 s2 = ((const float2*)gsum)[lane];
            float2 q2 = ((const float2*)gsq)[lane];
            float2 g2 = ((const float2*)gamma)[lane];
            float2 b2 = ((const float2*)beta)[lane];
            float mx = s2.x * invN, my = s2.y * invN;
            float vx = q2.x * invN - mx * mx, vy = q2.y * invN - my * my;
            scx = g2.x * rsqrtf(vx + BN_EPS); shx = b2.x - mx * scx;
            scy = g2.y * rsqrtf(vy + BN_EPS); shy = b2.y - my * scy;
        }
        // hoist self-loop row load so it overlaps the edge loop
        float2 hv = make_float2(0.f, 0.f);
        if (act) hv = ((const float2*)(h + (size_t)node * C))[lane];
        float ax = 0.f, ay = 0.f;
        for (int base = p0; base < p1; base += 64) {
            int nn = p1 - base; if (nn > 64) nn = 64;
            int2 e = make_int2(0, 0);
            if (lane < nn) e = ew[base + lane];
            int myc = e.x; float myw = __int_as_float(e.y);
            int j = 0;
            for (; j + 16 <= nn; j += 16) {
                int s[16]; float w[16];
                #pragma unroll
                for (int t = 0; t < 16; ++t) { s[t] = __shfl(myc, j + t); w[t] = __shfl(myw, j + t); }
                if (act) {
                    float2 v[16];
                    #pragma unroll
                    for (int t = 0; t < 16; ++t) v[t] = ((const float2*)(h + (size_t)s[t] * C))[lane];
                    #pragma unroll
                    for (int t = 0; t < 16; ++t) {
                        float vx = v[t].x, vy = v[t].y;
                        if (BN) {
                            vx = fmaxf(vx * scx + shx, 0.f);
                            vy = fmaxf(vy * scy + shy, 0.f);
                        }
                        ax += w[t] * vx; ay += w[t] * vy;
                    }
                }
            }
            for (; j + 4 <= nn; j += 4) {
                int s[4]; float w[4];
                #pragma unroll
                for (int t = 0; t < 4; ++t) { s[t] = __shfl(myc, j + t); w[t] = __shfl(myw, j + t); }
                if (act) {
                    float2 v[4];
                    #pragma unroll
                    for (int t = 0; t < 4; ++t) v[t] = ((const float2*)(h + (size_t)s[t] * C))[lane];
                    #pragma unroll
                    for (int t = 0; t < 4; ++t) {
                        float vx = v[t].x, vy = v[t].y;
                        if (BN) {
                            vx = fmaxf(vx * scx + shx, 0.f);
                            vy = fmaxf(vy * scy + shy, 0.f);
                        }
                        ax += w[t] * vx; ay += w[t] * vy;
                    }
                }
            }
            for (; j < nn; ++j) {
                int s0 = __shfl(myc, j);
                float w0 = __shfl(myw, j);
                if (act) {
                    float2 v = ((const float2*)(h + (size_t)s0 * C))[lane];
                    float vx = v.x, vy = v.y;
                    if (BN) {
                        vx = fmaxf(vx * scx + shx, 0.f);
                        vy = fmaxf(vy * scy + shy, 0.f);
                    }
                    ax += w0 * vx; ay += w0 * vy;
                }
            }
        }
        if (act) {
            float hx = hv.x, hy = hv.y;
            if (BN) {
                hx = fmaxf(hx * scx + shx, 0.f);
                hy = fmaxf(hy * scy + shy, 0.f);
            }
            float2 o;
            o.x = di * (ax + di * hx);
            o.y = di * (ay + di * hy);
            ((float2*)(a + (size_t)node * OS))[lane] = o;
        }
    } else {
        bool m0 = lane < C;
        float hv = 0.f;
        if (m0) hv = h[(size_t)node * C + lane];
        float acc0 = 0.f;
        for (int base = p0; base < p1; base += 64) {
            int nn = p1 - base; if (nn > 64) nn = 64;
            int2 e = make_int2(0, 0);
            if (lane < nn) e = ew[base + lane];
            int myc = e.x; float myw = __int_as_float(e.y);
            int j = 0;
            for (; j + 16 <= nn; j += 16) {
                int s[16]; float w[16];
                #pragma unroll
                for (int t = 0; t < 16; ++t) { s[t] = __shfl(myc, j + t); w[t] = __shfl(myw, j + t); }
                if (m0) {
                    float v[16];
                    #pragma unroll
                    for (int t = 0; t < 16; ++t) v[t] = h[(size_t)s[t] * C + lane];
                    #pragma unroll
                    for (int t = 0; t < 16; ++t) acc0 += w[t] * v[t];
                }
            }
            for (; j < nn; ++j) {
                int s0 = __shfl(myc, j);
                float w0 = __shfl(myw, j);
                if (m0) acc0 += w0 * h[(size_t)s0 * C + lane];
            }
        }
        if (lane < OS) {
            float r = 0.f;
            if (m0) r = di * (acc0 + di * hv);
            a[(size_t)node * OS + lane] = r;
        }
    }
}

// ---------------- CH-layer GEMM (512 threads; R7-proven for K=100) ----------------
// 64-row x 100-col tile, W (KPxCH) and A tile both in LDS, 2-barrier body,
// 400 compute threads own 4 rows x 4 cols. A row stride KP, pad zeroed.
template<int K, int KP>
__global__ __launch_bounds__(512) void k_gemm(
    const float* __restrict__ A, const float* __restrict__ W, const float* __restrict__ bias,
    float* __restrict__ Z, float* __restrict__ gsum, float* __restrict__ gsq) {
    __shared__ __align__(16) float wS[KP * CH];
    __shared__ __align__(16) float aS[64 * KP];
    __shared__ float sSum[CH], sSq[CH];
    int tid = threadIdx.x;
    for (int i = tid; i < CH; i += 512) { sSum[i] = 0.f; sSq[i] = 0.f; }
    for (int i = tid; i < KP * CH; i += 512) wS[i] = (i < K * CH) ? W[i] : 0.f;
    int row0 = blockIdx.x * 64;
    {
        const float* Ab = A + (size_t)row0 * KP;
        int maxI = (NNODES - row0) * KP;   // >= 64*KP except last block
        for (int i = tid; i < 64 * KP; i += 512) aS[i] = (i < maxI) ? Ab[i] : 0.f;
    }
    __syncthreads();
    if (tid < 400) {
        int ct = tid % 25, rt = tid / 25;  // ct 0..24, rt 0..15
        int c0 = ct * 4, r0 = rt * 4;
        float acc[4][4] = {};
        for (int k = 0; k < KP; k += 4) {
            float4 w0 = *(const float4*)&wS[(k + 0) * CH + c0];
            float4 w1 = *(const float4*)&wS[(k + 1) * CH + c0];
            float4 w2 = *(const float4*)&wS[(k + 2) * CH + c0];
            float4 w3 = *(const float4*)&wS[(k + 3) * CH + c0];
            #pragma unroll
            for (int j = 0; j < 4; ++j) {
                float4 av = *(const float4*)&aS[(r0 + j) * KP + k];
                acc[j][0] += av.x * w0.x + av.y * w1.x + av.z * w2.x + av.w * w3.x;
                acc[j][1] += av.x * w0.y + av.y * w1.y + av.z * w2.y + av.w * w3.y;
                acc[j][2] += av.x * w0.z + av.y * w1.z + av.z * w2.z + av.w * w3.z;
                acc[j][3] += av.x * w0.w + av.y * w1.w + av.z * w2.w + av.w * w3.w;
            }
        }
        float4 bv = *(const float4*)&bias[c0];
        float cs0 = 0, cs1 = 0, cs2 = 0, cs3 = 0, cq0 = 0, cq1 = 0, cq2 = 0, cq3 = 0;
        #pragma unroll
        for (int j = 0; j < 4; ++j) {
            int r = row0 + r0 + j;
            if (r < NNODES) {
                float z0 = acc[j][0] + bv.x, z1 = acc[j][1] + bv.y;
                float z2 = acc[j][2] + bv.z, z3 = acc[j][3] + bv.w;
                *reinterpret_cast<float4*>(&Z[(size_t)r * CH + c0]) = make_float4(z0, z1, z2, z3);
                cs0 += z0; cs1 += z1; cs2 += z2; cs3 += z3;
                cq0 += z0 * z0; cq1 += z1 * z1; cq2 += z2 * z2; cq3 += z3 * z3;
            }
        }
        atomicAdd(&sSum[c0], cs0); atomicAdd(&sSum[c0 + 1], cs1);
        atomicAdd(&sSum[c0 + 2], cs2); atomicAdd(&sSum[c0 + 3], cs3);
        atomicAdd(&sSq[c0], cq0); atomicAdd(&sSq[c0 + 1], cq1);
        atomicAdd(&sSq[c0 + 2], cq2); atomicAdd(&sSq[c0 + 3], cq3);
    }
    __syncthreads();
    if (tid < CH) { atomicAdd(&gsum[tid], sSum[tid]); atomicAdd(&gsq[tid], sSq[tid]); }
}

// ---------------- layer-0 GEMM (256 threads; R2-proven shape for small K) ----------------
// 64-row tile, 200 compute threads own 8 consecutive rows x 4 cols; K=33, KP=36.
// LDS ~24.4 KB -> high blocks/CU; small K needs fewer waves per block, not more.
__global__ __launch_bounds__(256) void k_gemm0(
    const float* __restrict__ A, const float* __restrict__ W, const float* __restrict__ bias,
    float* __restrict__ Z, float* __restrict__ gsum, float* __restrict__ gsq) {
    constexpr int K = CIN0, KP = 36;
    __shared__ __align__(16) float wS[KP * CH];
    __shared__ __align__(16) float aS[64 * KP];
    __shared__ float sSum[CH], sSq[CH];
    int tid = threadIdx.x;
    for (int i = tid; i < CH; i += 256) { sSum[i] = 0.f; sSq[i] = 0.f; }
    for (int i = tid; i < KP * CH; i += 256) wS[i] = (i < K * CH) ? W[i] : 0.f;
    int row0 = blockIdx.x * 64;
    {
        const float* Ab = A + (size_t)row0 * KP;
        int maxI = (NNODES - row0) * KP;
        for (int i = tid; i < 64 * KP; i += 256) aS[i] = (i < maxI) ? Ab[i] : 0.f;
    }
    __syncthreads();
    if (tid < 200) {
        int ct = tid % 25, rt = tid / 25;  // ct 0..24, rt 0..7
        int c0 = ct * 4, r0 = rt * 8;
        float acc[8][4] = {};
        for (int k = 0; k < KP; k += 4) {
            float4 w0 = *(const float4*)&wS[(k + 0) * CH + c0];
            float4 w1 = *(const float4*)&wS[(k + 1) * CH + c0];
            float4 w2 = *(const float4*)&wS[(k + 2) * CH + c0];
            float4 w3 = *(const float4*)&wS[(k + 3) * CH + c0];
            #pragma unroll
            for (int j = 0; j < 8; ++j) {
                float4 av = *(const float4*)&aS[(r0 + j) * KP + k];
                acc[j][0] += av.x * w0.x + av.y * w1.x + av.z * w2.x + av.w * w3.x;
                acc[j][1] += av.x * w0.y + av.y * w1.y + av.z * w2.y + av.w * w3.y;
                acc[j][2] += av.x * w0.z + av.y * w1.z + av.z * w2.z + av.w * w3.z;
                acc[j][3] += av.x * w0.w + av.y * w1.w + av.z * w2.w + av.w * w3.w;
            }
        }
        float4 bv = *(const float4*)&bias[c0];
        float cs0 = 0, cs1 = 0, cs2 = 0, cs3 = 0, cq0 = 0, cq1 = 0, cq2 = 0, cq3 = 0;
        #pragma unroll
        for (int j = 0; j < 8; ++j) {
            int r = row0 + r0 + j;
            if (r < NNODES) {
                float z0 = acc[j][0] + bv.x, z1 = acc[j][1] + bv.y;
                float z2 = acc[j][2] + bv.z, z3 = acc[j][3] + bv.w;
                *reinterpret_cast<float4*>(&Z[(size_t)r * CH + c0]) = make_float4(z0, z1, z2, z3);
                cs0 += z0; cs1 += z1; cs2 += z2; cs3 += z3;
                cq0 += z0 * z0; cq1 += z1 * z1; cq2 += z2 * z2; cq3 += z3 * z3;
            }
        }
        atomicAdd(&sSum[c0], cs0); atomicAdd(&sSum[c0 + 1], cs1);
        atomicAdd(&sSum[c0 + 2], cs2); atomicAdd(&sSum[c0 + 3], cs3);
        atomicAdd(&sSq[c0], cq0); atomicAdd(&sSq[c0 + 1], cq1);
        atomicAdd(&sSq[c0 + 2], cq2); atomicAdd(&sSq[c0 + 3], cq3);
    }
    __syncthreads();
    if (tid < CH) { atomicAdd(&gsum[tid], sSum[tid]); atomicAdd(&gsq[tid], sSq[tid]); }
}

// ---------------- global_add_pool of BN(z) (no relu); 4 row-chunks per graph ----------------
__global__ void k_pool(const float* __restrict__ Zl, const int* __restrict__ batch,
                       const float* __restrict__ gsum, const float* __restrict__ gsq,
                       const float* __restrict__ gamma, const float* __restrict__ beta,
                       float* __restrict__ g) {
    int gid = blockIdx.x;
    int part = blockIdx.y;
    int lo = 0, hi = NNODES;
    while (lo < hi) { int mid = (lo + hi) >> 1; if (batch[mid] < gid) lo = mid + 1; else hi = mid; }
    int start = lo;
    hi = NNODES;
    while (lo < hi) { int mid = (lo + hi) >> 1; if (batch[mid] < gid + 1) lo = mid + 1; else hi = mid; }
    int end = lo;
    int len = end - start;
    int cb = (len + 3) >> 2;
    int s = start + part * cb;
    int e = s + cb; if (e > end) e = end;
    if (s >= e) return;
    int c = threadIdx.x;
    if (c >= CH) return;
    float mean = gsum[c] * (1.f / NNODES);
    float var = gsq[c] * (1.f / NNODES) - mean * mean;
    float sc = gamma[c] * rsqrtf(var + BN_EPS);
    float sh = beta[c] - mean * sc;
    float acc = 0.f;
    for (int r = s; r < e; ++r) acc += Zl[(size_t)r * CH + c];
    atomicAdd(&g[gid * CH + c], acc * sc + (float)(e - s) * sh);
}

// ---------------- out = leakyrelu(g @ Wout + bout, 0.1) ----------------
__global__ __launch_bounds__(256) void k_out(const float* __restrict__ g,
                                             const float* __restrict__ Wout,
                                             const float* __restrict__ bout,
                                             float* __restrict__ out) {
    __shared__ float gS[CH];
    int gid = blockIdx.x, tid = threadIdx.x;
    if (tid < CH) gS[tid] = g[gid * CH + tid];
    __syncthreads();
    if (tid >= 200) return;
    float acc = bout[tid];
    for (int k = 0; k < CH; ++k) acc += gS[k] * Wout[k * 200 + tid];
    out[gid * 200 + tid] = acc > 0.f ? acc : 0.1f * acc;
}

extern "C" void kernel_launch(void* const* d_in, const int* in_sizes, int n_in,
                              void* d_out, int out_size, void* d_ws, size_t ws_size,
                              hipStream_t stream) {
    const float* x = (const float*)d_in[0];
    const int* ei = (const int*)d_in[1];
    const int* batch = (const int*)d_in[2];
    const float* W0 = (const float*)d_in[3];
    const float* Wrest = (const float*)d_in[4];
    const float* b = (const float*)d_in[5];
    const float* gamma = (const float*)d_in[6];
    const float* beta = (const float*)d_in[7];
    const float* Wout = (const float*)d_in[8];
    const float* bout = (const float*)d_in[9];
    float* out = (float*)d_out;
    const int* srcA = ei;
    const int* dstA = ei + NEDGES;

    char* wsb = (char*)d_ws;
    size_t off = 0;
    auto alloc = [&](size_t elems) -> void* {
        void* p = (void*)(wsb + off);
        off += ((elems + 7) & ~(size_t)7) * 4;
        return p;
    };
    int* cnt = (int*)alloc(NNODES);
    int* rowptr = (int*)alloc(NNODES + 1);
    int* cursor = (int*)alloc(NNODES);
    float* dinv = (float*)alloc(NNODES);
    int* scanBlk = (int*)alloc(64);
    int* scanOff = (int*)alloc(64);
    float* stats = (float*)alloc(1024);      // sums[4][128] | sumsq[4][128]
    int2* ew = (int2*)alloc(2 * (size_t)NEDGES);
    float* Abuf = (float*)alloc((size_t)NNODES * CH);
    float* Zbuf = (float*)alloc((size_t)NNODES * CH);
    float* gbuf = (float*)alloc((size_t)NGRAPH * CH);
    (void)ws_size; (void)n_in; (void)in_sizes; (void)out_size;

    hipLaunchKernelGGL(k_init, dim3((NNODES + 255) / 256), dim3(256), 0, stream, cnt, stats, gbuf);
    hipLaunchKernelGGL(k_hist, dim3((NEDGES + 255) / 256), dim3(256), 0, stream, dstA, cnt);
    hipLaunchKernelGGL(k_scan1, dim3(SCAN_BLOCKS), dim3(SCAN_TPB), 0, stream, cnt, rowptr, scanBlk, dinv);
    hipLaunchKernelGGL(k_scan2, dim3(1), dim3(64), 0, stream, scanBlk, scanOff);
    hipLaunchKernelGGL(k_scan3, dim3(SCAN_BLOCKS), dim3(SCAN_TPB), 0, stream, rowptr, cursor, scanOff);
    hipLaunchKernelGGL(k_scatter, dim3((NEDGES + 255) / 256), dim3(256), 0, stream,
                       srcA, dstA, dinv, cursor, ew);

    for (int l = 0; l < 4; ++l) {
        float* gs = stats + l * 128;
        float* gq = stats + 512 + l * 128;
        if (l == 0) {
            hipLaunchKernelGGL((k_aggregate<CIN0, 36, false>), dim3(12500), dim3(256), 0, stream,
                               x, Abuf, rowptr, ew, dinv,
                               (const float*)nullptr, (const float*)nullptr,
                               (const float*)nullptr, (const float*)nullptr);
            hipLaunchKernelGGL(k_gemm0, dim3((NNODES + 63) / 64), dim3(256), 0, stream,
                               Abuf, W0, b, Zbuf, gs, gq);
        } else {
            float* ps = stats + (l - 1) * 128;
            float* pq = stats + 512 + (l - 1) * 128;
            hipLaunchKernelGGL((k_aggregate<CH, CH, true>), dim3(12500), dim3(256), 0, stream,
                               Zbuf, Abuf, rowptr, ew, dinv,
                               ps, pq, gamma + (l - 1) * CH, beta + (l - 1) * CH);
            hipLaunchKernelGGL((k_gemm<CH, CH>), dim3((NNODES + 63) / 64), dim3(512), 0, stream,
                               Abuf, Wrest + (l - 1) * 10000, b + l * CH, Zbuf, gs, gq);
        }
    }
    hipLaunchKernelGGL(k_pool, dim3(NGRAPH, 4), dim3(128), 0, stream, Zbuf, batch,
                       stats + 3 * 128, stats + 512 + 3 * 128, gamma + 3 * CH, beta + 3 * CH, gbuf);
    hipLaunchKernelGGL(k_out, dim3(NGRAPH), dim3(256), 0, stream, gbuf, Wout, bout, out);
}